// Round 9
// baseline (223.663 us; speedup 1.0000x reference)
//
#include <hip/hip_runtime.h>
#include <hip/hip_bf16.h>
#include <math.h>

typedef __bf16 bf16;
typedef __bf16 bf16x8 __attribute__((ext_vector_type(8)));
typedef float floatx4 __attribute__((ext_vector_type(4)));

#define HIDDEN 1024
#define NHEADS 16
#define HDIM 64
#define TSEQ 2048
#define NBATCH 2
#define MTOT (NBATCH * TSEQ) /* 4096 */

// ---- async 16B global->LDS. lds addr must be wave-uniform base + lane*16. ----
__device__ inline void glds16(bf16* lds, const bf16* g)
{
  __builtin_amdgcn_global_load_lds(
      (const __attribute__((address_space(1))) unsigned int*)g,
      (__attribute__((address_space(3))) unsigned int*)lds, 16, 0, 0);
}

// ======================================================================
// prep: cvt x (blocks 0..2047) + cvt qkv_w (blocks 2048..3583)
// ======================================================================
__global__ __launch_bounds__(256) void prep_kernel(
    const float* __restrict__ x, bf16* __restrict__ xb,
    const float* __restrict__ qkv_w, bf16* __restrict__ qkv_wb)
{
  const int bid = blockIdx.x;
  const float* src = (bid < 2048) ? x : qkv_w;
  bf16* dst = (bid < 2048) ? xb : qkv_wb;
  const int i = (((bid < 2048) ? bid : bid - 2048) * 256 + threadIdx.x) * 8;
  const floatx4 u = *(const floatx4*)(src + i);
  const floatx4 v = *(const floatx4*)(src + i + 4);
  bf16x8 r;
#pragma unroll
  for (int j = 0; j < 4; j++) { r[j] = (bf16)u[j]; r[4 + j] = (bf16)v[j]; }
  *(bf16x8*)(dst + i) = r;
}

// ======================================================================
// GEMM (m97-style staging, 128x64 tile for TLP at K=1024):
// C[M,N] = A[M,K] @ W[N,K]^T + bias[N].  BK=32, 4 waves each 64x32
// (4x2 MFMA 16x16x32).  A staged via global_load_lds w=16.
// WF32: W is f32, converted to bf16 in registers during staging
// (A-glds path untouched) — used by gemm1 to skip a cvt pass.
// MODE 0: scatter into Q/K/V (b,h,t,d).  MODE 1: row-major f32 store.
// ======================================================================
template <int MODE, bool WF32>
__global__ __launch_bounds__(256) void gemm_bt(
    const bf16* __restrict__ A, const void* __restrict__ Wv,
    const float* __restrict__ bias, float* __restrict__ C,
    bf16* __restrict__ Qb, bf16* __restrict__ Kb, bf16* __restrict__ Vb,
    int M, int N, int K)
{
  __shared__ bf16 As[128 * 32];  // 8 KB
  __shared__ bf16 Bs[64 * 32];   // 4 KB

  const int tid  = threadIdx.x;
  const int lane = tid & 63;
  const int wv   = tid >> 6;
  const int quad = lane >> 4;
  const int l16  = lane & 15;
  const int m0 = blockIdx.y * 128;
  const int n0 = blockIdx.x * 64;
  const int wm = (wv & 1) * 64;
  const int wn = (wv >> 1) * 32;

  const int srow = lane >> 2;
  const int scol = (lane & 3) * 8;
  // f32 W staging decode: thread t -> row t>>2, cols (t&3)*8..+8;
  // LDS granule index = t (linear, conflict-free).
  const int rW = tid >> 2;
  const int cW = (tid & 3) * 8;

  floatx4 acc[4][2];
#pragma unroll
  for (int i = 0; i < 4; i++)
#pragma unroll
    for (int j = 0; j < 2; j++) acc[i][j] = (floatx4){0.f, 0.f, 0.f, 0.f};

  for (int k0 = 0; k0 < K; k0 += 32) {
    floatx4 wf0, wf1;
    if (WF32) {  // issue before barrier: overlaps prev compute
      const float* wp = (const float*)Wv + (size_t)(n0 + rW) * K + k0 + cW;
      wf0 = *(const floatx4*)wp;
      wf1 = *(const floatx4*)(wp + 4);
    }
    __syncthreads();  // prev iter's ds_reads done
    if (WF32) {
      bf16x8 wb;
#pragma unroll
      for (int j = 0; j < 4; j++) { wb[j] = (bf16)wf0[j]; wb[4 + j] = (bf16)wf1[j]; }
      *(bf16x8*)(Bs + rW * 32 + cW) = wb;
    }
    const bf16* ga = A + (size_t)(m0 + wv * 32 + srow) * K + k0 + scol;
    glds16(As + (wv * 32) * 32, ga);
    glds16(As + (wv * 32 + 16) * 32, ga + (size_t)16 * K);
    if (!WF32) {
      const bf16* gb = (const bf16*)Wv + (size_t)(n0 + wv * 16 + srow) * K + k0 + scol;
      glds16(Bs + (wv * 16) * 32, gb);
    }
    __syncthreads();  // drains vmcnt+lgkmcnt -> LDS populated

    bf16x8 af[4], bfr[2];
#pragma unroll
    for (int i = 0; i < 4; i++)
      af[i] = *(const bf16x8*)(As + (wm + i * 16 + l16) * 32 + quad * 8);
#pragma unroll
    for (int j = 0; j < 2; j++)
      bfr[j] = *(const bf16x8*)(Bs + (wn + j * 16 + l16) * 32 + quad * 8);
#pragma unroll
    for (int i = 0; i < 4; i++)
#pragma unroll
      for (int j = 0; j < 2; j++)
        acc[i][j] = __builtin_amdgcn_mfma_f32_16x16x32_bf16(af[i], bfr[j], acc[i][j], 0, 0, 0);
  }

  // ---- epilogue ----
#pragma unroll
  for (int i = 0; i < 4; i++) {
    const int gmBase = m0 + wm + i * 16 + quad * 4;
#pragma unroll
    for (int j = 0; j < 2; j++) {
      const int gn = n0 + wn + j * 16 + l16;
      const float bs = bias[gn];
      if (MODE == 1) {
#pragma unroll
        for (int r = 0; r < 4; r++)
          C[(size_t)(gmBase + r) * N + gn] = acc[i][j][r] + bs;
      } else {
        const int which = gn >> 10;
        const int rem = gn & 1023;
        const int h = rem >> 6, d = rem & 63;
        bf16* dst = (which == 0) ? Qb : (which == 1) ? Kb : Vb;
#pragma unroll
        for (int r = 0; r < 4; r++) {
          const int gm = gmBase + r;
          const int b_ = gm >> 11, t = gm & 2047;
          dst[((size_t)(b_ * NHEADS + h) * TSEQ + t) * HDIM + d] =
              (bf16)(acc[i][j][r] + bs);
        }
      }
    }
  }
}

// ======================================================================
// mid: RoPE in-place on Q,K (blocks 0..8191) + V->Vt transpose
// (blocks 8192..9215).  One launch, independent work.
// ======================================================================
__global__ __launch_bounds__(256) void mid_kernel(
    bf16* __restrict__ Q, bf16* __restrict__ K,
    const bf16* __restrict__ V, bf16* __restrict__ Vt)
{
  __shared__ bf16 tile[64][80];
  if (blockIdx.x < 8192) {
    const int idx = blockIdx.x * 256 + threadIdx.x;  // bh*65536 + t*32 + i
    const int i  = idx & 31;
    const int t  = (idx >> 5) & (TSEQ - 1);
    const int bh = idx >> 16;
    const float inv = powf(10000.0f, -(float)i * (1.0f / 32.0f));
    float s, c;
    sincosf((float)t * inv, &s, &c);
    const size_t base = ((size_t)bh * TSEQ + t) * HDIM;
    {
      const float x1 = (float)Q[base + i], x2 = (float)Q[base + i + 32];
      Q[base + i]      = (bf16)(x1 * c - x2 * s);
      Q[base + i + 32] = (bf16)(x1 * s + x2 * c);
    }
    {
      const float x1 = (float)K[base + i], x2 = (float)K[base + i + 32];
      K[base + i]      = (bf16)(x1 * c - x2 * s);
      K[base + i + 32] = (bf16)(x1 * s + x2 * c);
    }
  } else {
    const int bid = blockIdx.x - 8192;
    const int bh = bid >> 5;
    const int t0 = (bid & 31) * 64;
    const bf16* src = V + ((size_t)bh * TSEQ + t0) * HDIM;
    for (int c = threadIdx.x; c < 512; c += 256) {
      const int r = c >> 3, c8 = (c & 7) * 8;
      *(bf16x8*)&tile[r][c8] = *(const bf16x8*)(src + (size_t)r * HDIM + c8);
    }
    __syncthreads();
    bf16* dst = Vt + (size_t)bh * HDIM * TSEQ + t0;
    for (int c = threadIdx.x; c < 512; c += 256) {
      const int d = c >> 3, t8 = (c & 7) * 8;
      bf16x8 vv;
#pragma unroll
      for (int j = 0; j < 8; j++) vv[j] = tile[t8 + j][d];
      *(bf16x8*)(dst + (size_t)d * TSEQ + t8) = vv;
    }
  }
}

// ---- XOR granule swizzle for staging (reads lane-linear, conflict-free) ----
__device__ inline int swz(int g) { return (g & ~7) | ((g ^ (g >> 3) ^ (g >> 6)) & 7); }

// ======================================================================
// Flash attention v6 (unchanged from r8): flat 512 blocks, XCD-aware
// decode (4 bh per XCD -> 3 MB working set fits 4 MiB XCD L2); balanced
// pairing {31-p, p} = 33 chunks/block; register prefetch; swizzled LDS
// staging in MFMA fragment order; S^T = K.Q^T permuted-tile trick;
// in-register exp (no running max); PV from regs.
// ======================================================================
__global__ __launch_bounds__(256) void attn_kernel(
    const bf16* __restrict__ Q, const bf16* __restrict__ K,
    const bf16* __restrict__ Vt, bf16* __restrict__ O,
    const int* __restrict__ ids, const int* __restrict__ gidx)
{
  __shared__ bf16 Ks[4096];
  __shared__ bf16 Vs[4096];
  __shared__ int flags[4];

  const int tid  = threadIdx.x;
  const int lane = tid & 63;
  const int wv   = tid >> 6;
  const int quad = lane >> 4;
  const int l16  = lane & 15;

  const int xcd = blockIdx.x & 7;
  const int j   = blockIdx.x >> 3;
  const int bh  = xcd * 4 + (j >> 4);
  const int p   = j & 15;
  const int b  = bh >> 4;
  const int h  = bh & 15;

  const bf16* Qp = Q + (size_t)bh * TSEQ * HDIM;
  const bf16* Kp = K + (size_t)bh * TSEQ * HDIM;
  const bf16* Vp = Vt + (size_t)bh * HDIM * TSEQ;

  const int rK  = tid >> 3;
  const int dcK = tid & 7;
  const int gk = ((rK >> 2) & 1) * 128 + (dcK >> 2) * 64 +
                 ((dcK & 3) * 16 + (((rK >> 3) << 2) | (rK & 3)));
  const int kd0 = swz(gk) * 8, kd1 = swz(gk + 256) * 8;
  const int dV = tid >> 3;
  const int uV = tid & 7;
  const int gv = (uV >> 2) * 256 + (dV >> 4) * 64 + ((uV & 3) * 16 + (dV & 15));
  const int vd0 = swz(gv) * 8, vd1 = swz(gv + 128) * 8;

  const int g0v = gidx[0], g1v = gidx[1], g2v = gidx[2];

#pragma unroll
  for (int ph = 0; ph < 2; ph++) {
    const int qt = ph ? p : (31 - p);
    const int q0 = qt * 64 + wv * 16;

    const bf16x8 qf0 = *(const bf16x8*)(Qp + (size_t)(q0 + l16) * HDIM + quad * 8);
    const bf16x8 qf1 = *(const bf16x8*)(Qp + (size_t)(q0 + l16) * HDIM + 32 + quad * 8);

    const int myq = q0 + l16;
    const int myid = ids[b * TSEQ + myq];
    const int gl = (myid == g0v) | (myid == g1v) | (myid == g2v);
    flags[wv] = __any(gl);
    __syncthreads();
    const int anyg = flags[0] | flags[1] | flags[2] | flags[3];
    const int kmax = anyg ? TSEQ : (qt * 64 + 64);

    float lsum = 0.f;
    floatx4 o[4];
#pragma unroll
    for (int nt = 0; nt < 4; nt++) o[nt] = (floatx4){0.f, 0.f, 0.f, 0.f};

    bf16x8 kA = *(const bf16x8*)(Kp + tid * 8);
    bf16x8 kB = *(const bf16x8*)(Kp + 2048 + tid * 8);
    bf16x8 vA = *(const bf16x8*)(Vp + (size_t)dV * TSEQ + uV * 8);
    bf16x8 vB = *(const bf16x8*)(Vp + (size_t)(dV + 32) * TSEQ + uV * 8);

    for (int k0 = 0; k0 < kmax; k0 += 64) {
      __syncthreads();
      *(bf16x8*)(Ks + kd0) = kA;
      *(bf16x8*)(Ks + kd1) = kB;
      *(bf16x8*)(Vs + vd0) = vA;
      *(bf16x8*)(Vs + vd1) = vB;
      __syncthreads();

      if (k0 + 64 < kmax) {
        const bf16* kc = Kp + (size_t)(k0 + 64) * HDIM;
        kA = *(const bf16x8*)(kc + tid * 8);
        kB = *(const bf16x8*)(kc + 2048 + tid * 8);
        vA = *(const bf16x8*)(Vp + (size_t)dV * TSEQ + k0 + 64 + uV * 8);
        vB = *(const bf16x8*)(Vp + (size_t)(dV + 32) * TSEQ + k0 + 64 + uV * 8);
      }

#pragma unroll
      for (int g = 0; g < 2; g++) {
        const int kb = k0 + g * 32;
        const int rb = g * 256 + lane;
        const bf16x8 a00 = *(const bf16x8*)(Ks + swz(rb) * 8);
        const bf16x8 a01 = *(const bf16x8*)(Ks + swz(rb + 64) * 8);
        const bf16x8 a10 = *(const bf16x8*)(Ks + swz(rb + 128) * 8);
        const bf16x8 a11 = *(const bf16x8*)(Ks + swz(rb + 192) * 8);
        floatx4 s0 = (floatx4){0.f, 0.f, 0.f, 0.f};
        floatx4 s1 = (floatx4){0.f, 0.f, 0.f, 0.f};
        s0 = __builtin_amdgcn_mfma_f32_16x16x32_bf16(a00, qf0, s0, 0, 0, 0);
        s0 = __builtin_amdgcn_mfma_f32_16x16x32_bf16(a01, qf1, s0, 0, 0, 0);
        s1 = __builtin_amdgcn_mfma_f32_16x16x32_bf16(a10, qf0, s1, 0, 0, 0);
        s1 = __builtin_amdgcn_mfma_f32_16x16x32_bf16(a11, qf1, s1, 0, 0, 0);

        bf16x8 pf;
#pragma unroll
        for (int r = 0; r < 4; r++) {
          const int key0 = kb + quad * 8 + r;
          const int key1 = key0 + 4;
          const float p0 = (gl || key0 <= myq) ? __expf(s0[r] * 0.125f) : 0.f;
          const float p1 = (gl || key1 <= myq) ? __expf(s1[r] * 0.125f) : 0.f;
          lsum += p0 + p1;
          pf[r]     = (bf16)p0;
          pf[4 + r] = (bf16)p1;
        }

#pragma unroll
        for (int nt = 0; nt < 4; nt++) {
          const bf16x8 vf = *(const bf16x8*)(Vs + swz(g * 256 + nt * 64 + lane) * 8);
          o[nt] = __builtin_amdgcn_mfma_f32_16x16x32_bf16(pf, vf, o[nt], 0, 0, 0);
        }
      }
    }

    lsum += __shfl_xor(lsum, 16);
    lsum += __shfl_xor(lsum, 32);

#pragma unroll
    for (int r = 0; r < 4; r++) {
      const float inv = 1.0f / __shfl(lsum, quad * 4 + r);
      const int q = q0 + quad * 4 + r;
      const size_t rowoff = ((size_t)b * TSEQ + q) * HIDDEN + h * HDIM;
#pragma unroll
      for (int nt = 0; nt < 4; nt++)
        O[rowoff + nt * 16 + l16] = (bf16)(o[nt][r] * inv);
    }
  }
}

// ======================================================================
extern "C" void kernel_launch(void* const* d_in, const int* in_sizes, int n_in,
                              void* d_out, int out_size, void* d_ws, size_t ws_size,
                              hipStream_t stream)
{
  const float* x     = (const float*)d_in[0];
  const int*   ids   = (const int*)d_in[1];
  const float* qkv_w = (const float*)d_in[2];
  const float* qkv_b = (const float*)d_in[3];
  const float* out_w = (const float*)d_in[4];
  const float* out_b = (const float*)d_in[5];
  const int*   gidx  = (const int*)d_in[6];
  float* out = (float*)d_out;

  // ws (32 MiB): Q@0, K@8M, V@16M (O aliases V), slot24@24M: xb -> Vt.
  // qkv_wb (6 MiB) lives in d_out (dead until gemm1 overwrites it).
  char* ws = (char*)d_ws;
  bf16* Q      = (bf16*)(ws);
  bf16* Kb     = (bf16*)(ws + (size_t)(8u << 20));
  bf16* V      = (bf16*)(ws + (size_t)(16u << 20));
  bf16* slot24 = (bf16*)(ws + (size_t)(24u << 20));
  bf16* xb     = slot24;
  bf16* Vt     = slot24;
  bf16* qkv_wb = (bf16*)d_out;
  bf16* O      = V;

  // 0) convert x + qkv_w
  prep_kernel<<<3584, 256, 0, stream>>>(x, xb, qkv_w, qkv_wb);
  // 1) QKV projection -> Q/K/V (b,h,t,d)
  gemm_bt<0, false><<<dim3(3072 / 64, MTOT / 128), 256, 0, stream>>>(
      xb, qkv_wb, qkv_b, nullptr, Q, Kb, V, MTOT, 3 * HIDDEN, HIDDEN);
  // 2) RoPE (Q,K) + V->Vt (one launch; Vt overwrites xb, dead)
  mid_kernel<<<9216, 256, 0, stream>>>(Q, Kb, V, Vt);
  // 3) attention -> O (b,t,hidden); overwrites V
  attn_kernel<<<512, 256, 0, stream>>>(Q, Kb, Vt, O, ids, gidx);
  // 4) output projection (W = out_w f32, converted in staging) -> d_out
  gemm_bt<1, true><<<dim3(HIDDEN / 64, MTOT / 128), 256, 0, stream>>>(
      O, out_w, out_b, out, nullptr, nullptr, nullptr, MTOT, HIDDEN, HIDDEN);
}

// Round 10
// 204.786 us; speedup vs baseline: 1.0922x; 1.0922x over previous
//
#include <hip/hip_runtime.h>
#include <hip/hip_bf16.h>
#include <math.h>

typedef __bf16 bf16;
typedef __bf16 bf16x8 __attribute__((ext_vector_type(8)));
typedef float floatx4 __attribute__((ext_vector_type(4)));

#define HIDDEN 1024
#define NHEADS 16
#define HDIM 64
#define TSEQ 2048
#define NBATCH 2
#define MTOT (NBATCH * TSEQ) /* 4096 */

// ---- async 16B global->LDS. lds addr must be wave-uniform base + lane*16. ----
__device__ inline void glds16(bf16* lds, const bf16* g)
{
  __builtin_amdgcn_global_load_lds(
      (const __attribute__((address_space(1))) unsigned int*)g,
      (__attribute__((address_space(3))) unsigned int*)lds, 16, 0, 0);
}

// ======================================================================
// prep: cvt x (blocks 0..2047) + cvt qkv_w (blocks 2048..3583)
// ======================================================================
__global__ __launch_bounds__(256) void prep_kernel(
    const float* __restrict__ x, bf16* __restrict__ xb,
    const float* __restrict__ qkv_w, bf16* __restrict__ qkv_wb)
{
  const int bid = blockIdx.x;
  const float* src = (bid < 2048) ? x : qkv_w;
  bf16* dst = (bid < 2048) ? xb : qkv_wb;
  const int i = (((bid < 2048) ? bid : bid - 2048) * 256 + threadIdx.x) * 8;
  const floatx4 u = *(const floatx4*)(src + i);
  const floatx4 v = *(const floatx4*)(src + i + 4);
  bf16x8 r;
#pragma unroll
  for (int j = 0; j < 4; j++) { r[j] = (bf16)u[j]; r[4 + j] = (bf16)v[j]; }
  *(bf16x8*)(dst + i) = r;
}

// ======================================================================
// f32 -> bf16 bulk convert (out_w, after attn frees slot24)
// ======================================================================
__global__ __launch_bounds__(256) void cvt_f32_bf16(
    const float* __restrict__ src, bf16* __restrict__ dst, int n)
{
  const int i = (blockIdx.x * 256 + threadIdx.x) * 8;
  if (i >= n) return;
  const floatx4 u = *(const floatx4*)(src + i);
  const floatx4 v = *(const floatx4*)(src + i + 4);
  bf16x8 r;
#pragma unroll
  for (int j = 0; j < 4; j++) { r[j] = (bf16)u[j]; r[4 + j] = (bf16)v[j]; }
  *(bf16x8*)(dst + i) = r;
}

// ======================================================================
// gemm_qkv (r7-proven config): C = A[M,K] @ W[N,K]^T + bias, 128x128 tile,
// BK=32, 4 waves x (64x64 = 4x4 MFMA 16x16x32), global_load_lds w=16.
// Epilogue scatters into Q/K/V (b,h,t,d).  Grid (24, 32) = 768 blocks.
// ======================================================================
__global__ __launch_bounds__(256) void gemm_qkv(
    const bf16* __restrict__ A, const bf16* __restrict__ W,
    const float* __restrict__ bias,
    bf16* __restrict__ Qb, bf16* __restrict__ Kb, bf16* __restrict__ Vb,
    int M, int N, int K)
{
  __shared__ bf16 As[128 * 32];
  __shared__ bf16 Bs[128 * 32];

  const int tid  = threadIdx.x;
  const int lane = tid & 63;
  const int wv   = tid >> 6;
  const int quad = lane >> 4;
  const int l16  = lane & 15;
  const int m0 = blockIdx.y * 128;
  const int n0 = blockIdx.x * 128;
  const int wm = (wv >> 1) * 64;
  const int wn = (wv & 1) * 64;

  const int srow = lane >> 2;
  const int scol = (lane & 3) * 8;

  floatx4 acc[4][4];
#pragma unroll
  for (int i = 0; i < 4; i++)
#pragma unroll
    for (int j = 0; j < 4; j++) acc[i][j] = (floatx4){0.f, 0.f, 0.f, 0.f};

  for (int k0 = 0; k0 < K; k0 += 32) {
    __syncthreads();
    const bf16* ga = A + (size_t)(m0 + wv * 32 + srow) * K + k0 + scol;
    glds16(As + (wv * 32) * 32, ga);
    glds16(As + (wv * 32 + 16) * 32, ga + (size_t)16 * K);
    const bf16* gb = W + (size_t)(n0 + wv * 32 + srow) * K + k0 + scol;
    glds16(Bs + (wv * 32) * 32, gb);
    glds16(Bs + (wv * 32 + 16) * 32, gb + (size_t)16 * K);
    __syncthreads();

    bf16x8 af[4], bfr[4];
#pragma unroll
    for (int i = 0; i < 4; i++)
      af[i] = *(const bf16x8*)(As + (wm + i * 16 + l16) * 32 + quad * 8);
#pragma unroll
    for (int j = 0; j < 4; j++)
      bfr[j] = *(const bf16x8*)(Bs + (wn + j * 16 + l16) * 32 + quad * 8);
#pragma unroll
    for (int i = 0; i < 4; i++)
#pragma unroll
      for (int j = 0; j < 4; j++)
        acc[i][j] = __builtin_amdgcn_mfma_f32_16x16x32_bf16(af[i], bfr[j], acc[i][j], 0, 0, 0);
  }

#pragma unroll
  for (int i = 0; i < 4; i++) {
    const int gmBase = m0 + wm + i * 16 + quad * 4;
#pragma unroll
    for (int j = 0; j < 4; j++) {
      const int gn = n0 + wn + j * 16 + l16;
      const float bs = bias[gn];
      const int which = gn >> 10;
      const int rem = gn & 1023;
      const int h = rem >> 6, d = rem & 63;
      bf16* dst = (which == 0) ? Qb : (which == 1) ? Kb : Vb;
#pragma unroll
      for (int r = 0; r < 4; r++) {
        const int gm = gmBase + r;
        const int b_ = gm >> 11, t = gm & 2047;
        dst[((size_t)(b_ * NHEADS + h) * TSEQ + t) * HDIM + d] =
            (bf16)(acc[i][j][r] + bs);
      }
    }
  }
}

// ======================================================================
// gemm_out (r7-proven config): same tile, row-major f32 store.
// Grid (8, 32) = 256 blocks.
// ======================================================================
__global__ __launch_bounds__(256) void gemm_out(
    const bf16* __restrict__ A, const bf16* __restrict__ W,
    const float* __restrict__ bias, float* __restrict__ C,
    int M, int N, int K)
{
  __shared__ bf16 As[128 * 32];
  __shared__ bf16 Bs[128 * 32];

  const int tid  = threadIdx.x;
  const int lane = tid & 63;
  const int wv   = tid >> 6;
  const int quad = lane >> 4;
  const int l16  = lane & 15;
  const int m0 = blockIdx.y * 128;
  const int n0 = blockIdx.x * 128;
  const int wm = (wv >> 1) * 64;
  const int wn = (wv & 1) * 64;

  const int srow = lane >> 2;
  const int scol = (lane & 3) * 8;

  floatx4 acc[4][4];
#pragma unroll
  for (int i = 0; i < 4; i++)
#pragma unroll
    for (int j = 0; j < 4; j++) acc[i][j] = (floatx4){0.f, 0.f, 0.f, 0.f};

  for (int k0 = 0; k0 < K; k0 += 32) {
    __syncthreads();
    const bf16* ga = A + (size_t)(m0 + wv * 32 + srow) * K + k0 + scol;
    glds16(As + (wv * 32) * 32, ga);
    glds16(As + (wv * 32 + 16) * 32, ga + (size_t)16 * K);
    const bf16* gb = W + (size_t)(n0 + wv * 32 + srow) * K + k0 + scol;
    glds16(Bs + (wv * 32) * 32, gb);
    glds16(Bs + (wv * 32 + 16) * 32, gb + (size_t)16 * K);
    __syncthreads();

    bf16x8 af[4], bfr[4];
#pragma unroll
    for (int i = 0; i < 4; i++)
      af[i] = *(const bf16x8*)(As + (wm + i * 16 + l16) * 32 + quad * 8);
#pragma unroll
    for (int j = 0; j < 4; j++)
      bfr[j] = *(const bf16x8*)(Bs + (wn + j * 16 + l16) * 32 + quad * 8);
#pragma unroll
    for (int i = 0; i < 4; i++)
#pragma unroll
      for (int j = 0; j < 4; j++)
        acc[i][j] = __builtin_amdgcn_mfma_f32_16x16x32_bf16(af[i], bfr[j], acc[i][j], 0, 0, 0);
  }

#pragma unroll
  for (int i = 0; i < 4; i++) {
    const int gmBase = m0 + wm + i * 16 + quad * 4;
#pragma unroll
    for (int j = 0; j < 4; j++) {
      const int gn = n0 + wn + j * 16 + l16;
      const float bs = bias[gn];
#pragma unroll
      for (int r = 0; r < 4; r++)
        C[(size_t)(gmBase + r) * N + gn] = acc[i][j][r] + bs;
    }
  }
}

// ======================================================================
// mid: RoPE in-place on Q,K (blocks 0..8191) + V->Vt transpose
// (blocks 8192..9215). exp2f instead of powf (1 trans op).
// ======================================================================
__global__ __launch_bounds__(256) void mid_kernel(
    bf16* __restrict__ Q, bf16* __restrict__ K,
    const bf16* __restrict__ V, bf16* __restrict__ Vt)
{
  __shared__ bf16 tile[64][80];
  if (blockIdx.x < 8192) {
    const int idx = blockIdx.x * 256 + threadIdx.x;  // bh*65536 + t*32 + i
    const int i  = idx & 31;
    const int t  = (idx >> 5) & (TSEQ - 1);
    const int bh = idx >> 16;
    // 10000^(-i/32) = exp2(-i * log2(10000)/32), log2(10000)=13.287712
    const float inv = exp2f((float)i * -0.41524100f);
    float s, c;
    sincosf((float)t * inv, &s, &c);
    const size_t base = ((size_t)bh * TSEQ + t) * HDIM;
    {
      const float x1 = (float)Q[base + i], x2 = (float)Q[base + i + 32];
      Q[base + i]      = (bf16)(x1 * c - x2 * s);
      Q[base + i + 32] = (bf16)(x1 * s + x2 * c);
    }
    {
      const float x1 = (float)K[base + i], x2 = (float)K[base + i + 32];
      K[base + i]      = (bf16)(x1 * c - x2 * s);
      K[base + i + 32] = (bf16)(x1 * s + x2 * c);
    }
  } else {
    const int bid = blockIdx.x - 8192;
    const int bh = bid >> 5;
    const int t0 = (bid & 31) * 64;
    const bf16* src = V + ((size_t)bh * TSEQ + t0) * HDIM;
    for (int c = threadIdx.x; c < 512; c += 256) {
      const int r = c >> 3, c8 = (c & 7) * 8;
      *(bf16x8*)&tile[r][c8] = *(const bf16x8*)(src + (size_t)r * HDIM + c8);
    }
    __syncthreads();
    bf16* dst = Vt + (size_t)bh * HDIM * TSEQ + t0;
    for (int c = threadIdx.x; c < 512; c += 256) {
      const int d = c >> 3, t8 = (c & 7) * 8;
      bf16x8 vv;
#pragma unroll
      for (int j = 0; j < 8; j++) vv[j] = tile[t8 + j][d];
      *(bf16x8*)(dst + (size_t)d * TSEQ + t8) = vv;
    }
  }
}

// ---- XOR granule swizzle for staging (reads lane-linear, conflict-free) ----
__device__ inline int swz(int g) { return (g & ~7) | ((g ^ (g >> 3) ^ (g >> 6)) & 7); }

// ======================================================================
// Flash attention v6 (unchanged): flat 512 blocks, XCD-aware decode
// (4 bh per XCD -> 3 MB working set fits 4 MiB XCD L2); balanced pairing
// {31-p, p} = 33 chunks/block; register prefetch; swizzled LDS staging in
// MFMA fragment order; S^T = K.Q^T permuted-tile trick; in-register exp.
// ======================================================================
__global__ __launch_bounds__(256) void attn_kernel(
    const bf16* __restrict__ Q, const bf16* __restrict__ K,
    const bf16* __restrict__ Vt, bf16* __restrict__ O,
    const int* __restrict__ ids, const int* __restrict__ gidx)
{
  __shared__ bf16 Ks[4096];
  __shared__ bf16 Vs[4096];
  __shared__ int flags[4];

  const int tid  = threadIdx.x;
  const int lane = tid & 63;
  const int wv   = tid >> 6;
  const int quad = lane >> 4;
  const int l16  = lane & 15;

  const int xcd = blockIdx.x & 7;
  const int j   = blockIdx.x >> 3;
  const int bh  = xcd * 4 + (j >> 4);
  const int p   = j & 15;
  const int b  = bh >> 4;
  const int h  = bh & 15;

  const bf16* Qp = Q + (size_t)bh * TSEQ * HDIM;
  const bf16* Kp = K + (size_t)bh * TSEQ * HDIM;
  const bf16* Vp = Vt + (size_t)bh * HDIM * TSEQ;

  const int rK  = tid >> 3;
  const int dcK = tid & 7;
  const int gk = ((rK >> 2) & 1) * 128 + (dcK >> 2) * 64 +
                 ((dcK & 3) * 16 + (((rK >> 3) << 2) | (rK & 3)));
  const int kd0 = swz(gk) * 8, kd1 = swz(gk + 256) * 8;
  const int dV = tid >> 3;
  const int uV = tid & 7;
  const int gv = (uV >> 2) * 256 + (dV >> 4) * 64 + ((uV & 3) * 16 + (dV & 15));
  const int vd0 = swz(gv) * 8, vd1 = swz(gv + 128) * 8;

  const int g0v = gidx[0], g1v = gidx[1], g2v = gidx[2];

#pragma unroll
  for (int ph = 0; ph < 2; ph++) {
    const int qt = ph ? p : (31 - p);
    const int q0 = qt * 64 + wv * 16;

    const bf16x8 qf0 = *(const bf16x8*)(Qp + (size_t)(q0 + l16) * HDIM + quad * 8);
    const bf16x8 qf1 = *(const bf16x8*)(Qp + (size_t)(q0 + l16) * HDIM + 32 + quad * 8);

    const int myq = q0 + l16;
    const int myid = ids[b * TSEQ + myq];
    const int gl = (myid == g0v) | (myid == g1v) | (myid == g2v);
    flags[wv] = __any(gl);
    __syncthreads();
    const int anyg = flags[0] | flags[1] | flags[2] | flags[3];
    const int kmax = anyg ? TSEQ : (qt * 64 + 64);

    float lsum = 0.f;
    floatx4 o[4];
#pragma unroll
    for (int nt = 0; nt < 4; nt++) o[nt] = (floatx4){0.f, 0.f, 0.f, 0.f};

    bf16x8 kA = *(const bf16x8*)(Kp + tid * 8);
    bf16x8 kB = *(const bf16x8*)(Kp + 2048 + tid * 8);
    bf16x8 vA = *(const bf16x8*)(Vp + (size_t)dV * TSEQ + uV * 8);
    bf16x8 vB = *(const bf16x8*)(Vp + (size_t)(dV + 32) * TSEQ + uV * 8);

    for (int k0 = 0; k0 < kmax; k0 += 64) {
      __syncthreads();
      *(bf16x8*)(Ks + kd0) = kA;
      *(bf16x8*)(Ks + kd1) = kB;
      *(bf16x8*)(Vs + vd0) = vA;
      *(bf16x8*)(Vs + vd1) = vB;
      __syncthreads();

      if (k0 + 64 < kmax) {
        const bf16* kc = Kp + (size_t)(k0 + 64) * HDIM;
        kA = *(const bf16x8*)(kc + tid * 8);
        kB = *(const bf16x8*)(kc + 2048 + tid * 8);
        vA = *(const bf16x8*)(Vp + (size_t)dV * TSEQ + k0 + 64 + uV * 8);
        vB = *(const bf16x8*)(Vp + (size_t)(dV + 32) * TSEQ + k0 + 64 + uV * 8);
      }

#pragma unroll
      for (int g = 0; g < 2; g++) {
        const int kb = k0 + g * 32;
        const int rb = g * 256 + lane;
        const bf16x8 a00 = *(const bf16x8*)(Ks + swz(rb) * 8);
        const bf16x8 a01 = *(const bf16x8*)(Ks + swz(rb + 64) * 8);
        const bf16x8 a10 = *(const bf16x8*)(Ks + swz(rb + 128) * 8);
        const bf16x8 a11 = *(const bf16x8*)(Ks + swz(rb + 192) * 8);
        floatx4 s0 = (floatx4){0.f, 0.f, 0.f, 0.f};
        floatx4 s1 = (floatx4){0.f, 0.f, 0.f, 0.f};
        s0 = __builtin_amdgcn_mfma_f32_16x16x32_bf16(a00, qf0, s0, 0, 0, 0);
        s0 = __builtin_amdgcn_mfma_f32_16x16x32_bf16(a01, qf1, s0, 0, 0, 0);
        s1 = __builtin_amdgcn_mfma_f32_16x16x32_bf16(a10, qf0, s1, 0, 0, 0);
        s1 = __builtin_amdgcn_mfma_f32_16x16x32_bf16(a11, qf1, s1, 0, 0, 0);

        bf16x8 pf;
#pragma unroll
        for (int r = 0; r < 4; r++) {
          const int key0 = kb + quad * 8 + r;
          const int key1 = key0 + 4;
          const float p0 = (gl || key0 <= myq) ? __expf(s0[r] * 0.125f) : 0.f;
          const float p1 = (gl || key1 <= myq) ? __expf(s1[r] * 0.125f) : 0.f;
          lsum += p0 + p1;
          pf[r]     = (bf16)p0;
          pf[4 + r] = (bf16)p1;
        }

#pragma unroll
        for (int nt = 0; nt < 4; nt++) {
          const bf16x8 vf = *(const bf16x8*)(Vs + swz(g * 256 + nt * 64 + lane) * 8);
          o[nt] = __builtin_amdgcn_mfma_f32_16x16x32_bf16(pf, vf, o[nt], 0, 0, 0);
        }
      }
    }

    lsum += __shfl_xor(lsum, 16);
    lsum += __shfl_xor(lsum, 32);

#pragma unroll
    for (int r = 0; r < 4; r++) {
      const float inv = 1.0f / __shfl(lsum, quad * 4 + r);
      const int q = q0 + quad * 4 + r;
      const size_t rowoff = ((size_t)b * TSEQ + q) * HIDDEN + h * HDIM;
#pragma unroll
      for (int nt = 0; nt < 4; nt++)
        O[rowoff + nt * 16 + l16] = (bf16)(o[nt][r] * inv);
    }
  }
}

// ======================================================================
extern "C" void kernel_launch(void* const* d_in, const int* in_sizes, int n_in,
                              void* d_out, int out_size, void* d_ws, size_t ws_size,
                              hipStream_t stream)
{
  const float* x     = (const float*)d_in[0];
  const int*   ids   = (const int*)d_in[1];
  const float* qkv_w = (const float*)d_in[2];
  const float* qkv_b = (const float*)d_in[3];
  const float* out_w = (const float*)d_in[4];
  const float* out_b = (const float*)d_in[5];
  const int*   gidx  = (const int*)d_in[6];
  float* out = (float*)d_out;

  // ws (32 MiB): Q@0, K@8M, V@16M (O aliases V), slot24@24M multiplexed:
  //   xb (until gemm_qkv done) -> Vt (mid..attn) -> out_wb (post-attn).
  // qkv_wb (6 MiB) lives in d_out (dead until gemm_out overwrites it).
  char* ws = (char*)d_ws;
  bf16* Q      = (bf16*)(ws);
  bf16* Kb     = (bf16*)(ws + (size_t)(8u << 20));
  bf16* V      = (bf16*)(ws + (size_t)(16u << 20));
  bf16* slot24 = (bf16*)(ws + (size_t)(24u << 20));
  bf16* xb     = slot24;
  bf16* Vt     = slot24;
  bf16* out_wb = slot24;
  bf16* qkv_wb = (bf16*)d_out;
  bf16* O      = V;

  // 0) convert x + qkv_w
  prep_kernel<<<3584, 256, 0, stream>>>(x, xb, qkv_w, qkv_wb);
  // 1) QKV projection -> Q/K/V (b,h,t,d)
  gemm_qkv<<<dim3(3072 / 128, MTOT / 128), 256, 0, stream>>>(
      xb, qkv_wb, qkv_b, Q, Kb, V, MTOT, 3 * HIDDEN, HIDDEN);
  // 2) RoPE (Q,K) + V->Vt (one launch; Vt overwrites xb, dead)
  mid_kernel<<<9216, 256, 0, stream>>>(Q, Kb, V, Vt);
  // 3) attention -> O (b,t,hidden); overwrites V
  attn_kernel<<<512, 256, 0, stream>>>(Q, Kb, Vt, O, ids, gidx);
  // 4) convert out_w (overwrites Vt, dead)
  cvt_f32_bf16<<<512, 256, 0, stream>>>(out_w, out_wb, HIDDEN * HIDDEN);
  // 5) output projection -> d_out (overwrites qkv_wb, dead)
  gemm_out<<<dim3(HIDDEN / 128, MTOT / 128), 256, 0, stream>>>(
      O, out_wb, out_b, out, MTOT, HIDDEN, HIDDEN);
}